// Round 1
// baseline (124.918 us; speedup 1.0000x reference)
//
#include <hip/hip_runtime.h>

// Problem constants (match reference)
#define HH 256
#define WW 256
#define NB 2
#define NN 128
#define NSTEPS_K 50

// jnp.gradient along axis 0, evaluated on the fly from pred
__device__ __forceinline__ float grad_y(const float* __restrict__ f, int i, int j) {
    if (i == 0) return f[WW + j] - f[j];
    if (i == HH - 1) return f[(HH - 1) * WW + j] - f[(HH - 2) * WW + j];
    return 0.5f * (f[(i + 1) * WW + j] - f[(i - 1) * WW + j]);
}
// jnp.gradient along axis 1
__device__ __forceinline__ float grad_x(const float* __restrict__ f, int i, int j) {
    if (j == 0) return f[i * WW + 1] - f[i * WW];
    if (j == WW - 1) return f[i * WW + WW - 1] - f[i * WW + WW - 2];
    return 0.5f * (f[i * WW + j + 1] - f[i * WW + j - 1]);
}

// One block per batch, one thread per node. 50 sequential active-contour steps.
__global__ void evolve_kernel(const float* __restrict__ pred,
                              const float* __restrict__ nodes_in,
                              float* __restrict__ nodes_out) {
    const int b = blockIdx.x;
    const int i = threadIdx.x;            // 0..127
    const float* f = pred + b * HH * WW;

    __shared__ float sy[NN], sx[NN], s2y[NN], s2x[NN];

    float y = nodes_in[(b * NN + i) * 2 + 0];
    float x = nodes_in[(b * NN + i) * 2 + 1];
    sy[i] = y; sx[i] = x;
    const int ip = (i + 1) & (NN - 1);
    const int im = (i - 1) & (NN - 1);
    __syncthreads();

    for (int s = 0; s < NSTEPS_K; ++s) {
        // d2 = x[i+1] + x[i-1] - 2x[i]  (circular)
        float d2y = (sy[ip] + sy[im]) - 2.0f * y;
        float d2x = (sx[ip] + sx[im]) - 2.0f * x;
        s2y[i] = d2y; s2x[i] = d2x;
        __syncthreads();
        // d4 = d2[i+1] + d2[i-1] - 2*d2[i]
        float d4y = (s2y[ip] + s2y[im]) - 2.0f * d2y;
        float d4x = (s2x[ip] + s2x[im]) - 2.0f * d2x;

        // bilerp of (gy, gx) at (y, x), clipped like the reference
        float yc = fminf(fmaxf(y, 0.0f), 254.999f);
        float xc = fminf(fmaxf(x, 0.0f), 254.999f);
        int y0 = (int)floorf(yc), x0 = (int)floorf(xc);
        int y1 = y0 + 1, x1 = x0 + 1;
        float wy = yc - (float)y0, wx = xc - (float)x0;
        float w00 = (1.0f - wy) * (1.0f - wx);
        float w01 = (1.0f - wy) * wx;
        float w10 = wy * (1.0f - wx);
        float w11 = wy * wx;
        float by = grad_y(f, y0, x0) * w00 + grad_y(f, y0, x1) * w01 +
                   grad_y(f, y1, x0) * w10 + grad_y(f, y1, x1) * w11;
        float bx = grad_x(f, y0, x0) * w00 + grad_x(f, y0, x1) * w01 +
                   grad_x(f, y1, x0) * w10 + grad_x(f, y1, x1) * w11;
        float exty = -10.0f * by;   // -EXTGRADFAC * bilerp(gy)
        float extx = -10.0f * bx;

        y = y + 0.1f * (0.01f * d2y - 0.01f * d4y + exty);
        x = x + 0.1f * (0.01f * d2x - 0.01f * d4x + extx);
        y = fminf(fmaxf(y, 0.0f), 255.0f);
        x = fminf(fmaxf(x, 0.0f), 255.0f);

        __syncthreads();            // all reads of sy/sx and s2y/s2x for this step done
        sy[i] = y; sx[i] = x;
        __syncthreads();            // new positions visible
    }

    nodes_out[(b * NN + i) * 2 + 0] = y;
    nodes_out[(b * NN + i) * 2 + 1] = x;
}

// grid = (HH*WW/256, NB), block = 256. One pixel per thread; min point-segment
// distance over 128 segments; per-block partial sum of squared error.
__global__ void render_kernel(const float* __restrict__ pred,
                              const float* __restrict__ nodes,
                              float* __restrict__ partials) {
    const int b = blockIdx.y;
    const int chunk = blockIdx.x;    // 0..255
    const int tid = threadIdx.x;     // 0..255

    __shared__ float p0y[NN], p0x[NN], sdy[NN], sdx[NN], sidd[NN];
    if (tid < NN) {
        float ay = nodes[(b * NN + tid) * 2 + 0];
        float ax = nodes[(b * NN + tid) * 2 + 1];
        int j = (tid + 1) & (NN - 1);
        float cy = nodes[(b * NN + j) * 2 + 0];
        float cx = nodes[(b * NN + j) * 2 + 1];
        float ddy = cy - ay, ddx = cx - ax;
        p0y[tid] = ay; p0x[tid] = ax;
        sdy[tid] = ddy; sdx[tid] = ddx;
        sidd[tid] = 1.0f / (ddy * ddy + ddx * ddx + 1e-8f);
    }
    __syncthreads();

    const int pix = chunk * 256 + tid;          // 0..65535
    const float qy = (float)(pix >> 8);         // row
    const float qx = (float)(pix & (WW - 1));   // col

    float minr2 = 1e30f;
#pragma unroll 8
    for (int s = 0; s < NN; ++s) {
        float qpy = qy - p0y[s];
        float qpx = qx - p0x[s];
        float t = (qpy * sdy[s] + qpx * sdx[s]) * sidd[s];
        t = fminf(fmaxf(t, 0.0f), 1.0f);
        float ry = qpy - t * sdy[s];
        float rx = qpx - t * sdx[s];
        float r2 = ry * ry + rx * rx;
        minr2 = fminf(minr2, r2);
    }
    float dist = fminf(sqrtf(minr2 + 1e-12f), 15.0f);
    float e = pred[b * HH * WW + pix] - dist;
    float se = e * e;

    // block reduce (256 threads = 4 waves)
    for (int off = 32; off > 0; off >>= 1) se += __shfl_down(se, off);
    __shared__ float red[4];
    if ((tid & 63) == 0) red[tid >> 6] = se;
    __syncthreads();
    if (tid == 0) partials[b * 256 + chunk] = (red[0] + red[1]) + (red[2] + red[3]);
}

// Deterministic reduction of the 512 block partials -> mean -> d_out[0]
__global__ void finalize_kernel(const float* __restrict__ partials,
                                float* __restrict__ out) {
    const int tid = threadIdx.x;   // 256
    float v = partials[tid] + partials[tid + 256];
    for (int off = 32; off > 0; off >>= 1) v += __shfl_down(v, off);
    __shared__ float red[4];
    if ((tid & 63) == 0) red[tid >> 6] = v;
    __syncthreads();
    if (tid == 0)
        out[0] = ((red[0] + red[1]) + (red[2] + red[3])) * (1.0f / (float)(NB * HH * WW));
}

extern "C" void kernel_launch(void* const* d_in, const int* in_sizes, int n_in,
                              void* d_out, int out_size, void* d_ws, size_t ws_size,
                              hipStream_t stream) {
    const float* pred = (const float*)d_in[0];    // (B,1,H,W) f32
    const float* nodes = (const float*)d_in[1];   // (B,N,2) f32
    float* ws = (float*)d_ws;
    float* partials = ws;          // 512 floats
    float* fnodes = ws + 512;      // 512 floats (final nodes)

    evolve_kernel<<<dim3(NB), dim3(NN), 0, stream>>>(pred, nodes, fnodes);
    render_kernel<<<dim3(HH * WW / 256, NB), dim3(256), 0, stream>>>(pred, fnodes, partials);
    finalize_kernel<<<dim3(1), dim3(256), 0, stream>>>(partials, (float*)d_out);
}

// Round 2
// 64.755 us; speedup vs baseline: 1.9291x; 1.9291x over previous
//
#include <hip/hip_runtime.h>

// Problem constants (match reference)
#define HH 256
#define WW 256
#define NB 2
#define NN 128
#define NSTEPS_K 50

// Branchless bilerp of (gy, gx) = jnp.gradient(pred) at point (y, x).
// 12 distinct loads; edge cases of jnp.gradient handled via clamped row/col
// indices + 0.5/1.0 scale selects (algebraically identical to the branchy form).
__device__ __forceinline__ void sample_grad(const float* __restrict__ f,
                                            float y, float x,
                                            float& by, float& bx) {
    float yc = fminf(fmaxf(y, 0.0f), 254.999f);
    float xc = fminf(fmaxf(x, 0.0f), 254.999f);
    int r0 = (int)yc, c0 = (int)xc;          // floor (values >= 0)
    int r1 = r0 + 1, c1 = c0 + 1;
    float wy = yc - (float)r0, wx = xc - (float)c0;
    int rm = max(r0 - 1, 0), rp = min(r1 + 1, HH - 1);
    int cm = max(c0 - 1, 0), cp = min(c1 + 1, WW - 1);
    float sy0 = (r0 == 0) ? 1.0f : 0.5f;          // one-sided diff at top edge
    float sy1 = (r1 == HH - 1) ? 1.0f : 0.5f;     // one-sided diff at bottom edge
    float sx0 = (c0 == 0) ? 1.0f : 0.5f;
    float sx1 = (c1 == WW - 1) ? 1.0f : 0.5f;

    const float* fr0 = f + (r0 << 8);
    const float* fr1 = f + (r1 << 8);
    const float* frm = f + (rm << 8);
    const float* frp = f + (rp << 8);
    // 12 independent loads -> single vmcnt wait
    float f00 = fr0[c0], f01 = fr0[c1];
    float f10 = fr1[c0], f11 = fr1[c1];
    float f0m = fr0[cm], f0p = fr0[cp];
    float f1m = fr1[cm], f1p = fr1[cp];
    float fm0 = frm[c0], fm1 = frm[c1];
    float fp0 = frp[c0], fp1 = frp[c1];

    // gradient values at the 4 bilerp corners
    float gy00 = sy0 * (f10 - fm0);
    float gy01 = sy0 * (f11 - fm1);
    float gy10 = sy1 * (fp0 - f00);
    float gy11 = sy1 * (fp1 - f01);
    float gx00 = sx0 * (f01 - f0m);
    float gx01 = sx1 * (f0p - f00);
    float gx10 = sx0 * (f11 - f1m);
    float gx11 = sx1 * (f1p - f10);

    float u = 1.0f - wy, v = 1.0f - wx;
    by = gy00 * u * v + gy01 * u * wx + gy10 * wy * v + gy11 * wy * wx;
    bx = gx00 * u * v + gx01 * u * wx + gx10 * wy * v + gx11 * wy * wx;
}

// One block (= ONE wave) per batch; lane l owns nodes 2l and 2l+1 in registers.
// Circular d2/d4 stencils via __shfl; zero barriers; 24 loads/lane/step with
// one wait. 50 strictly sequential steps (latency-bound by construction).
__global__ __launch_bounds__(64, 1) void evolve_kernel(
        const float* __restrict__ pred,
        const float* __restrict__ nodes_in,
        float* __restrict__ nodes_out) {
    const int b = blockIdx.x;
    const int l = threadIdx.x;            // 0..63
    const float* f = pred + b * HH * WW;
    const int pl = (l + 63) & 63;         // prev lane (circular)
    const int nl = (l + 1) & 63;          // next lane (circular)

    // nodes layout (B, N, 2): lane l's two nodes are 4 consecutive floats
    float4 nd = ((const float4*)nodes_in)[b * 64 + l];
    float y0n = nd.x, x0n = nd.y;         // node 2l
    float y1n = nd.z, x1n = nd.w;         // node 2l+1

    for (int s = 0; s < NSTEPS_K; ++s) {
        // ---- external force (issues 24 loads; overlaps the shuffle chain) ----
        float by0, bx0, by1, bx1;
        sample_grad(f, y0n, x0n, by0, bx0);
        sample_grad(f, y1n, x1n, by1, bx1);

        // ---- neighbor exchange: prev lane holds nodes 2l-2,2l-1; next holds 2l+2,2l+3
        float py1 = __shfl(y1n, pl);      // node 2l-1 y
        float px1 = __shfl(x1n, pl);
        float nyy0 = __shfl(y0n, nl);     // node 2l+2 y
        float nxx0 = __shfl(x0n, nl);

        // d2 = (x[i+1] + x[i-1]) - 2 x[i]   (reference op order)
        float d2y0 = (y1n + py1) - 2.0f * y0n;
        float d2x0 = (x1n + px1) - 2.0f * x0n;
        float d2y1 = (nyy0 + y0n) - 2.0f * y1n;
        float d2x1 = (nxx0 + x0n) - 2.0f * x1n;

        // second shuffle round for d4 = (d2[i+1] + d2[i-1]) - 2 d2[i]
        float pd2y1 = __shfl(d2y1, pl);   // d2 of node 2l-1
        float pd2x1 = __shfl(d2x1, pl);
        float nd2y0 = __shfl(d2y0, nl);   // d2 of node 2l+2
        float nd2x0 = __shfl(d2x0, nl);
        float d4y0 = (d2y1 + pd2y1) - 2.0f * d2y0;
        float d4x0 = (d2x1 + pd2x1) - 2.0f * d2x0;
        float d4y1 = (nd2y0 + d2y0) - 2.0f * d2y1;
        float d4x1 = (nd2x0 + d2x0) - 2.0f * d2x1;

        // x += STEPSZ*(ALPHA*d2 - BETA*d4 + ext); clip to [0, 255]
        y0n = y0n + 0.1f * ((0.01f * d2y0 - 0.01f * d4y0) + (-10.0f * by0));
        x0n = x0n + 0.1f * ((0.01f * d2x0 - 0.01f * d4x0) + (-10.0f * bx0));
        y1n = y1n + 0.1f * ((0.01f * d2y1 - 0.01f * d4y1) + (-10.0f * by1));
        x1n = x1n + 0.1f * ((0.01f * d2x1 - 0.01f * d4x1) + (-10.0f * bx1));
        y0n = fminf(fmaxf(y0n, 0.0f), 255.0f);
        x0n = fminf(fmaxf(x0n, 0.0f), 255.0f);
        y1n = fminf(fmaxf(y1n, 0.0f), 255.0f);
        x1n = fminf(fmaxf(x1n, 0.0f), 255.0f);
    }

    float4 out; out.x = y0n; out.y = x0n; out.z = y1n; out.w = x1n;
    ((float4*)nodes_out)[b * 64 + l] = out;
}

// grid = (HH*WW/256, NB), block = 256. One pixel per thread; min point-segment
// distance over 128 segments; per-block partial sum of squared error.
__global__ void render_kernel(const float* __restrict__ pred,
                              const float* __restrict__ nodes,
                              float* __restrict__ partials) {
    const int b = blockIdx.y;
    const int chunk = blockIdx.x;    // 0..255
    const int tid = threadIdx.x;     // 0..255

    __shared__ float p0y[NN], p0x[NN], sdy[NN], sdx[NN], sidd[NN];
    if (tid < NN) {
        float ay = nodes[(b * NN + tid) * 2 + 0];
        float ax = nodes[(b * NN + tid) * 2 + 1];
        int j = (tid + 1) & (NN - 1);
        float cy = nodes[(b * NN + j) * 2 + 0];
        float cx = nodes[(b * NN + j) * 2 + 1];
        float ddy = cy - ay, ddx = cx - ax;
        p0y[tid] = ay; p0x[tid] = ax;
        sdy[tid] = ddy; sdx[tid] = ddx;
        sidd[tid] = 1.0f / (ddy * ddy + ddx * ddx + 1e-8f);
    }
    __syncthreads();

    const int pix = chunk * 256 + tid;          // 0..65535
    const float qy = (float)(pix >> 8);         // row
    const float qx = (float)(pix & (WW - 1));   // col

    float minr2 = 1e30f;
#pragma unroll 8
    for (int s = 0; s < NN; ++s) {
        float qpy = qy - p0y[s];
        float qpx = qx - p0x[s];
        float t = (qpy * sdy[s] + qpx * sdx[s]) * sidd[s];
        t = fminf(fmaxf(t, 0.0f), 1.0f);
        float ry = qpy - t * sdy[s];
        float rx = qpx - t * sdx[s];
        float r2 = ry * ry + rx * rx;
        minr2 = fminf(minr2, r2);
    }
    float dist = fminf(sqrtf(minr2 + 1e-12f), 15.0f);
    float e = pred[b * HH * WW + pix] - dist;
    float se = e * e;

    // block reduce (256 threads = 4 waves)
    for (int off = 32; off > 0; off >>= 1) se += __shfl_down(se, off);
    __shared__ float red[4];
    if ((tid & 63) == 0) red[tid >> 6] = se;
    __syncthreads();
    if (tid == 0) partials[b * 256 + chunk] = (red[0] + red[1]) + (red[2] + red[3]);
}

// Deterministic reduction of the 512 block partials -> mean -> d_out[0]
__global__ void finalize_kernel(const float* __restrict__ partials,
                                float* __restrict__ out) {
    const int tid = threadIdx.x;   // 256
    float v = partials[tid] + partials[tid + 256];
    for (int off = 32; off > 0; off >>= 1) v += __shfl_down(v, off);
    __shared__ float red[4];
    if ((tid & 63) == 0) red[tid >> 6] = v;
    __syncthreads();
    if (tid == 0)
        out[0] = ((red[0] + red[1]) + (red[2] + red[3])) * (1.0f / (float)(NB * HH * WW));
}

extern "C" void kernel_launch(void* const* d_in, const int* in_sizes, int n_in,
                              void* d_out, int out_size, void* d_ws, size_t ws_size,
                              hipStream_t stream) {
    const float* pred = (const float*)d_in[0];    // (B,1,H,W) f32
    const float* nodes = (const float*)d_in[1];   // (B,N,2) f32
    float* ws = (float*)d_ws;
    float* partials = ws;          // 512 floats
    float* fnodes = ws + 512;      // 512 floats (final nodes)

    evolve_kernel<<<dim3(NB), dim3(64), 0, stream>>>(pred, nodes, fnodes);
    render_kernel<<<dim3(HH * WW / 256, NB), dim3(256), 0, stream>>>(pred, fnodes, partials);
    finalize_kernel<<<dim3(1), dim3(256), 0, stream>>>(partials, (float*)d_out);
}